// Round 1
// baseline (6845.184 us; speedup 1.0000x reference)
//
#include <hip/hip_runtime.h>
#include <hip/hip_bf16.h>

// CascadedAttention on MI355X.
// Pipeline: (1) x -> fp16, (2) Ua -> fp16 transposed, (3) UaH = x@Ua + Ba2 via
// mfma_f32_16x16x32_f16 (fp16 out), (4) recurrence: one 1024-thread WG per batch,
// 150 steps in-kernel, streaming x_h/UaH_h (both fp16, 157 MB total -> LLC-resident).
// Ba3 dropped: softmax is shift-invariant.

typedef _Float16 h8 __attribute__((ext_vector_type(8)));
typedef _Float16 h4 __attribute__((ext_vector_type(4)));
typedef _Float16 h2 __attribute__((ext_vector_type(2)));
typedef float    f4 __attribute__((ext_vector_type(4)));
typedef float    f2 __attribute__((ext_vector_type(2)));

#define B_   256
#define T_   150
#define F_   1024
#define U_   28
#define TU3  84   // 3*U

__device__ __forceinline__ float fast_exp(float x) {
    return __builtin_amdgcn_exp2f(x * 1.4426950408889634f);
}
__device__ __forceinline__ float fast_tanh(float x) {
    // tanh(x) = 1 - 2/(exp(2x)+1); exp2-based, v_rcp. Saturates correctly at +-inf.
    float e = __builtin_amdgcn_exp2f(x * 2.8853900817779268f);
    float r = __builtin_amdgcn_rcpf(e + 1.0f);
    return 1.0f - 2.0f * r;
}
__device__ __forceinline__ float fast_sigmoid(float x) {
    float e = __builtin_amdgcn_exp2f(-x * 1.4426950408889634f);
    return __builtin_amdgcn_rcpf(1.0f + e);
}

// ---------------- fp32 -> fp16 convert (vectorized) ----------------
__global__ void k_cvt(const float* __restrict__ in, _Float16* __restrict__ out, int n4) {
    int i = blockIdx.x * blockDim.x + threadIdx.x;
    int stride = gridDim.x * blockDim.x;
    const f4* in4 = (const f4*)in;
    h4* out4 = (h4*)out;
    for (; i < n4; i += stride) {
        f4 v = in4[i];
        h4 o;
        o[0] = (_Float16)v[0]; o[1] = (_Float16)v[1];
        o[2] = (_Float16)v[2]; o[3] = (_Float16)v[3];
        out4[i] = o;
    }
}

// ---------------- Ua (1024x1024) -> fp16 transposed ----------------
__global__ void k_cvt_transpose(const float* __restrict__ in, _Float16* __restrict__ out) {
    int idx = blockIdx.x * blockDim.x + threadIdx.x;   // grid covers exactly 1024*1024
    int r = idx >> 10, c = idx & 1023;
    out[(c << 10) + r] = (_Float16)in[idx];            // coalesced read, scattered 2B write (1M elems, cheap)
}

// ---------------- GEMM: UaH = x_h @ Ua + Ba2  (M=38400,N=1024,K=1024) ----------------
#define BM 128
#define BN 128
#define BK 32
#define LDT 40   // padded K-stride in halves (80B rows: 2-4 way LDS conflicts only)

__global__ __launch_bounds__(256) void k_gemm(
    const _Float16* __restrict__ A,   // [M][1024] row-major (x_h)
    const _Float16* __restrict__ Bt,  // [N][1024] row-major (Ua transposed)
    const float*    __restrict__ bias,// Ba2 [1024]
    _Float16*       __restrict__ C)   // [M][1024] fp16
{
    __shared__ _Float16 As[BM][LDT];
    __shared__ _Float16 Bs[BN][LDT];
    const int K = 1024;
    int bm = blockIdx.y, bn = blockIdx.x;
    int tid = threadIdx.x;
    int lane = tid & 63, wid = tid >> 6;
    int wm = wid >> 1, wn = wid & 1;           // 2x2 waves, 64x64 each
    f4 acc[4][4];
#pragma unroll
    for (int i = 0; i < 4; i++)
#pragma unroll
        for (int j = 0; j < 4; j++) { f4 z = {0.f, 0.f, 0.f, 0.f}; acc[i][j] = z; }

    int row0 = bm * BM, col0 = bn * BN;
    for (int kt = 0; kt < K; kt += BK) {
        // stage 128x32 halves for A and Bt: 512 slots, slot s -> row s>>2, seg s&3
#pragma unroll
        for (int p = 0; p < 2; ++p) {
            int s = tid + p * 256;
            int r = s >> 2, seg = s & 3;
            h8 va = *(const h8*)(A  + (size_t)(row0 + r) * K + kt + seg * 8);
            *(h8*)(&As[r][seg * 8]) = va;
            h8 vb = *(const h8*)(Bt + (size_t)(col0 + r) * K + kt + seg * 8);
            *(h8*)(&Bs[r][seg * 8]) = vb;
        }
        __syncthreads();
        int kq = (lane >> 4) * 8;   // k-offset of this lane's 8 elements
        h8 af[4], bf[4];
#pragma unroll
        for (int mi = 0; mi < 4; mi++) af[mi] = *(const h8*)(&As[wm * 64 + mi * 16 + (lane & 15)][kq]);
#pragma unroll
        for (int ni = 0; ni < 4; ni++) bf[ni] = *(const h8*)(&Bs[wn * 64 + ni * 16 + (lane & 15)][kq]);
#pragma unroll
        for (int mi = 0; mi < 4; mi++)
#pragma unroll
            for (int ni = 0; ni < 4; ni++)
                acc[mi][ni] = __builtin_amdgcn_mfma_f32_16x16x32_f16(af[mi], bf[ni], acc[mi][ni], 0, 0, 0);
        __syncthreads();
    }
    // epilogue: C/D layout col=lane&15, row=(lane>>4)*4+reg
    int rq = (lane >> 4) * 4, cq = lane & 15;
#pragma unroll
    for (int mi = 0; mi < 4; mi++)
#pragma unroll
        for (int ni = 0; ni < 4; ni++) {
            int gc = col0 + wn * 64 + ni * 16 + cq;
            float bv = bias[gc];
#pragma unroll
            for (int j = 0; j < 4; j++) {
                int gr = row0 + wm * 64 + mi * 16 + rq + j;
                C[(size_t)gr * 1024 + gc] = (_Float16)(acc[mi][ni][j] + bv);
            }
        }
}

// ---------------- recurrence: one WG (1024 thr) per batch, 150 steps ----------------
__global__ __launch_bounds__(1024) void k_recur(
    const _Float16* __restrict__ xh,   // [B][T][F] fp16
    const _Float16* __restrict__ uah,  // [B][T][F] fp16
    const float* __restrict__ Wa,      // [U][F]
    const float* __restrict__ Va,      // [F]
    const float* __restrict__ Ba1,     // [F]
    const float* __restrict__ gk,      // [F][3U]
    const float* __restrict__ grk,     // [U][3U]
    const float* __restrict__ gbias,   // [2][3U]
    float* __restrict__ out)           // [B][T][U]
{
    __shared__ float sVa[F_];
    __shared__ float sWaS[F_];
    __shared__ float sCtx[F_];
    __shared__ float sGrk[U_][TU3];
    __shared__ float sGb[2][TU3];
    __shared__ float sScore[T_ + 2];
    __shared__ float sH[U_ + 4];
    __shared__ float sPart[12][TU3];
    __shared__ float sXz[TU3];
    __shared__ float sHz[TU3];

    int b = blockIdx.x;
    int tid = threadIdx.x;
    int lane = tid & 63, wvid = tid >> 6;    // 16 waves

    for (int i = tid; i < F_; i += 1024) sVa[i] = Va[i];
    for (int i = tid; i < U_ * TU3; i += 1024) ((float*)sGrk)[i] = grk[i];
    for (int i = tid; i < 2 * TU3; i += 1024) ((float*)sGb)[i] = gbias[i];
    if (tid < U_) sH[tid] = 0.f;
    __syncthreads();

    const _Float16* xb = xh  + (size_t)b * T_ * F_;
    const _Float16* ub = uah + (size_t)b * T_ * F_;
    float* ob = out + (size_t)b * T_ * U_;

    for (int t = 0; t < T_; ++t) {
        // ---- phase 1: WaS[f] = h @ Wa + Ba1 (f = tid; Wa stays L2-hot)
        {
            int f = tid;
            float acc = Ba1[f];
#pragma unroll
            for (int u = 0; u < U_; ++u) acc += sH[u] * Wa[u * F_ + f];
            sWaS[f] = acc;
        }
        __syncthreads();
        // ---- phase 2: scores[r] = Va . tanh(UaH[r] + WaS); one row per wave-iteration
        for (int r = wvid; r < T_; r += 16) {
            const h2* prow = (const h2*)(ub + (size_t)r * F_);
            float acc = 0.f;
#pragma unroll
            for (int k = 0; k < 8; ++k) {
                int fp = lane + k * 64;          // f-pair index; f = 2*fp (coalesced dwords)
                h2 uv = prow[fp];
                f2 wv2 = *(const f2*)(&sWaS[2 * fp]);
                f2 vv  = *(const f2*)(&sVa[2 * fp]);
                float s0 = (float)uv[0] + wv2[0];
                float s1 = (float)uv[1] + wv2[1];
                acc += fast_tanh(s0) * vv[0];
                acc += fast_tanh(s1) * vv[1];
            }
#pragma unroll
            for (int off = 32; off; off >>= 1) acc += __shfl_xor(acc, off, 64);
            if (lane == 0) sScore[r] = acc;
        }
        __syncthreads();
        // ---- phase 3: softmax over 150 scores (wave 0)
        if (wvid == 0) {
            float v0 = (lane < T_)        ? sScore[lane]        : -1e30f;
            float v1 = (lane + 64 < T_)   ? sScore[lane + 64]   : -1e30f;
            float v2 = (lane + 128 < T_)  ? sScore[lane + 128]  : -1e30f;
            float m = fmaxf(v0, fmaxf(v1, v2));
#pragma unroll
            for (int off = 32; off; off >>= 1) m = fmaxf(m, __shfl_xor(m, off, 64));
            float e0 = (lane < T_)       ? fast_exp(v0 - m) : 0.f;
            float e1 = (lane + 64 < T_)  ? fast_exp(v1 - m) : 0.f;
            float e2 = (lane + 128 < T_) ? fast_exp(v2 - m) : 0.f;
            float s = e0 + e1 + e2;
#pragma unroll
            for (int off = 32; off; off >>= 1) s += __shfl_xor(s, off, 64);
            float rs = __builtin_amdgcn_rcpf(s);
            if (lane < T_)       sScore[lane]       = e0 * rs;
            if (lane + 64 < T_)  sScore[lane + 64]  = e1 * rs;
            if (lane + 128 < T_) sScore[lane + 128] = e2 * rs;
        }
        __syncthreads();
        // ---- phase 4: ctx[f] = sum_r a[r]*x[r][f]; threads 0..511 handle f-pairs
        if (tid < 512) {
            float c0 = 0.f, c1 = 0.f;
            const h2* px = (const h2*)xb + tid;
            for (int r = 0; r < T_; ++r) {
                float a = sScore[r];
                h2 xv = px[(size_t)r * (F_ / 2)];
                c0 += a * (float)xv[0];
                c1 += a * (float)xv[1];
            }
            sCtx[2 * tid] = c0; sCtx[2 * tid + 1] = c1;
        }
        __syncthreads();
        // ---- phase 5: xz partials: fc = tid/84 (12 chunks), j = tid%84
        if (tid < 12 * TU3) {
            int fc = tid / TU3, j = tid - fc * TU3;
            float acc = 0.f;
            for (int f = fc; f < F_; f += 12) acc += sCtx[f] * gk[f * TU3 + j];
            sPart[fc][j] = acc;
        }
        __syncthreads();
        // ---- phase 6: finish xz; hz = h @ grk + bias1
        if (tid < TU3) {
            float xz = sGb[0][tid];
#pragma unroll
            for (int fc = 0; fc < 12; ++fc) xz += sPart[fc][tid];
            sXz[tid] = xz;
            float hz = sGb[1][tid];
#pragma unroll
            for (int u = 0; u < U_; ++u) hz += sH[u] * sGrk[u][tid];
            sHz[tid] = hz;
        }
        __syncthreads();
        // ---- phase 7: gates + state update + output
        if (tid < U_) {
            float z  = fast_sigmoid(sXz[tid] + sHz[tid]);
            float r  = fast_sigmoid(sXz[U_ + tid] + sHz[U_ + tid]);
            float hh = fast_tanh(sXz[2 * U_ + tid] + r * sHz[2 * U_ + tid]);
            float hn = z * sH[tid] + (1.f - z) * hh;
            sH[tid] = hn;
            ob[(size_t)t * U_ + tid] = hn;
        }
        __syncthreads();
    }
}

extern "C" void kernel_launch(void* const* d_in, const int* in_sizes, int n_in,
                              void* d_out, int out_size, void* d_ws, size_t ws_size,
                              hipStream_t stream) {
    (void)in_sizes; (void)n_in; (void)out_size; (void)ws_size;
    const float* x   = (const float*)d_in[0];
    const float* Wa  = (const float*)d_in[1];
    const float* Ua  = (const float*)d_in[2];
    const float* Va  = (const float*)d_in[3];
    const float* Ba1 = (const float*)d_in[4];
    const float* Ba2 = (const float*)d_in[5];
    // d_in[6] = Ba3: softmax shift-invariant, dropped.
    const float* gk  = (const float*)d_in[7];
    const float* grk = (const float*)d_in[8];
    const float* gb  = (const float*)d_in[9];
    float* out = (float*)d_out;

    const size_t NX = (size_t)B_ * T_ * F_;          // 39,321,600
    _Float16* xh  = (_Float16*)d_ws;                 // NX halves
    _Float16* uat = xh + NX;                         // 1024*1024 halves
    _Float16* uah = uat + (size_t)F_ * F_;           // NX halves  (total ws: ~152 MB)

    k_cvt<<<2048, 256, 0, stream>>>(x, xh, (int)(NX / 4));
    k_cvt_transpose<<<(F_ * F_) / 256, 256, 0, stream>>>(Ua, uat);
    dim3 gg(F_ / BN, (B_ * T_) / BM);                // (8, 300)
    k_gemm<<<gg, 256, 0, stream>>>(xh, uat, Ba2, uah);
    k_recur<<<B_, 1024, 0, stream>>>(xh, uah, Wa, Va, Ba1, gk, grk, gb, out);
}

// Round 3
// 2667.378 us; speedup vs baseline: 2.5663x; 2.5663x over previous
//
#include <hip/hip_runtime.h>
#include <hip/hip_bf16.h>

// CascadedAttention on MI355X — round 2 (resubmit: round-1 bench hit infra timeout).
// Algebraic rewrite: xz = ctx@gk = a . XG where XG = x@gk is loop-invariant.
// -> recurrence no longer reads x at all; ctx/xz phases collapse to a 150x84 dot
//    against LDS-resident XG. Remaining stream: UaH (fp16) only.
// Pipeline: (1) x->fp16, (2) Ua->fp16^T, (3) UaH = x@Ua + Ba2 (MFMA, fp16 out),
// (4) XG = x@gk (MFMA, fp16 out), (5) recurrence: 1 WG (1024 thr) per batch.

typedef _Float16 h8 __attribute__((ext_vector_type(8)));
typedef _Float16 h4 __attribute__((ext_vector_type(4)));
typedef _Float16 h2 __attribute__((ext_vector_type(2)));
typedef float    f4 __attribute__((ext_vector_type(4)));
typedef float    f2 __attribute__((ext_vector_type(2)));

#define B_   256
#define T_   150
#define F_   1024
#define U_   28
#define TU3  84   // 3*U

__device__ __forceinline__ float fast_exp(float x) {
    return __builtin_amdgcn_exp2f(x * 1.4426950408889634f);
}
__device__ __forceinline__ float fast_tanh(float x) {
    float e = __builtin_amdgcn_exp2f(x * 2.8853900817779268f);
    float r = __builtin_amdgcn_rcpf(e + 1.0f);
    return 1.0f - 2.0f * r;
}
__device__ __forceinline__ float fast_sigmoid(float x) {
    float e = __builtin_amdgcn_exp2f(-x * 1.4426950408889634f);
    return __builtin_amdgcn_rcpf(1.0f + e);
}

// ---------------- fp32 -> fp16 convert ----------------
__global__ void k_cvt(const float* __restrict__ in, _Float16* __restrict__ out, int n4) {
    int i = blockIdx.x * blockDim.x + threadIdx.x;
    int stride = gridDim.x * blockDim.x;
    const f4* in4 = (const f4*)in;
    h4* out4 = (h4*)out;
    for (; i < n4; i += stride) {
        f4 v = in4[i];
        h4 o;
        o[0] = (_Float16)v[0]; o[1] = (_Float16)v[1];
        o[2] = (_Float16)v[2]; o[3] = (_Float16)v[3];
        out4[i] = o;
    }
}

// ---------------- Ua (1024x1024) -> fp16 transposed ----------------
__global__ void k_cvt_transpose(const float* __restrict__ in, _Float16* __restrict__ out) {
    int idx = blockIdx.x * blockDim.x + threadIdx.x;
    int r = idx >> 10, c = idx & 1023;
    out[(c << 10) + r] = (_Float16)in[idx];
}

// ---------------- GEMM: UaH = x_h @ Ua + Ba2 (M=38400,N=1024,K=1024) ----------------
#define BM 128
#define BN 128
#define BK 32
#define LDT 40

__global__ __launch_bounds__(256) void k_gemm(
    const _Float16* __restrict__ A,
    const _Float16* __restrict__ Bt,
    const float*    __restrict__ bias,
    _Float16*       __restrict__ C)
{
    __shared__ _Float16 As[BM][LDT];
    __shared__ _Float16 Bs[BN][LDT];
    const int K = 1024;
    int bm = blockIdx.y, bn = blockIdx.x;
    int tid = threadIdx.x;
    int lane = tid & 63, wid = tid >> 6;
    int wm = wid >> 1, wn = wid & 1;
    f4 acc[4][4];
#pragma unroll
    for (int i = 0; i < 4; i++)
#pragma unroll
        for (int j = 0; j < 4; j++) { f4 z = {0.f, 0.f, 0.f, 0.f}; acc[i][j] = z; }

    int row0 = bm * BM, col0 = bn * BN;
    for (int kt = 0; kt < K; kt += BK) {
#pragma unroll
        for (int p = 0; p < 2; ++p) {
            int s = tid + p * 256;
            int r = s >> 2, seg = s & 3;
            h8 va = *(const h8*)(A  + (size_t)(row0 + r) * K + kt + seg * 8);
            *(h8*)(&As[r][seg * 8]) = va;
            h8 vb = *(const h8*)(Bt + (size_t)(col0 + r) * K + kt + seg * 8);
            *(h8*)(&Bs[r][seg * 8]) = vb;
        }
        __syncthreads();
        int kq = (lane >> 4) * 8;
        h8 af[4], bf[4];
#pragma unroll
        for (int mi = 0; mi < 4; mi++) af[mi] = *(const h8*)(&As[wm * 64 + mi * 16 + (lane & 15)][kq]);
#pragma unroll
        for (int ni = 0; ni < 4; ni++) bf[ni] = *(const h8*)(&Bs[wn * 64 + ni * 16 + (lane & 15)][kq]);
#pragma unroll
        for (int mi = 0; mi < 4; mi++)
#pragma unroll
            for (int ni = 0; ni < 4; ni++)
                acc[mi][ni] = __builtin_amdgcn_mfma_f32_16x16x32_f16(af[mi], bf[ni], acc[mi][ni], 0, 0, 0);
        __syncthreads();
    }
    int rq = (lane >> 4) * 4, cq = lane & 15;
#pragma unroll
    for (int mi = 0; mi < 4; mi++)
#pragma unroll
        for (int ni = 0; ni < 4; ni++) {
            int gc = col0 + wn * 64 + ni * 16 + cq;
            float bv = bias[gc];
#pragma unroll
            for (int j = 0; j < 4; j++) {
                int gr = row0 + wm * 64 + mi * 16 + rq + j;
                C[(size_t)gr * 1024 + gc] = (_Float16)(acc[mi][ni][j] + bv);
            }
        }
}

// ---------------- GEMM: XG = x_h @ gk (M=38400, N=84 pad 96, K=1024), fp16 out ---------
#define XLD 72   // 144 B rows (9x16B): aligned, 2-way LDS conflicts only

__global__ __launch_bounds__(256) void k_gemm_xg(
    const _Float16* __restrict__ A,   // [38400][1024] fp16 (x_h)
    const float*    __restrict__ gk,  // [1024][84] fp32
    _Float16*       __restrict__ C)   // [38400][84] fp16
{
    __shared__ _Float16 As[128][XLD];
    __shared__ _Float16 Bs[96][XLD];
    int tid = threadIdx.x;
    int lane = tid & 63, wid = tid >> 6;
    int wm = wid >> 1, wn = wid & 1;           // 2x2 waves: 64 rows x 48 cols each
    int row0 = blockIdx.x * 128;
    f4 acc[4][3];
#pragma unroll
    for (int i = 0; i < 4; i++)
#pragma unroll
        for (int j = 0; j < 3; j++) { f4 z = {0.f, 0.f, 0.f, 0.f}; acc[i][j] = z; }

    // zero pad rows 84..95 of Bs once (never rewritten)
    if (tid < 432) { h2 z; z[0] = (_Float16)0.f; z[1] = (_Float16)0.f; ((h2*)&Bs[84][0])[tid] = z; }

    for (int kt = 0; kt < 1024; kt += 64) {
        // A tile: 128x64 halves = 1024 h8 slots
#pragma unroll
        for (int p = 0; p < 4; ++p) {
            int s = tid + p * 256;
            int r = s >> 3, seg = s & 7;
            *(h8*)(&As[r][seg * 8]) = *(const h8*)(A + (size_t)(row0 + r) * 1024 + kt + seg * 8);
        }
        // B tile: 84 rows(j) x 64(k) from gk[kt+k][j], on-the-fly transpose+cvt
#pragma unroll
        for (int p = 0; p < 21; ++p) {
            int s = tid + p * 256;           // 0..5375
            int j = s % 84, k = s / 84;
            Bs[j][k] = (_Float16)gk[(size_t)(kt + k) * 84 + j];
        }
        __syncthreads();
#pragma unroll
        for (int kk = 0; kk < 64; kk += 32) {
            int kq = kk + (lane >> 4) * 8;
            h8 af[4], bf[3];
#pragma unroll
            for (int mi = 0; mi < 4; mi++) af[mi] = *(const h8*)(&As[wm * 64 + mi * 16 + (lane & 15)][kq]);
#pragma unroll
            for (int ni = 0; ni < 3; ni++) bf[ni] = *(const h8*)(&Bs[wn * 48 + ni * 16 + (lane & 15)][kq]);
#pragma unroll
            for (int mi = 0; mi < 4; mi++)
#pragma unroll
                for (int ni = 0; ni < 3; ni++)
                    acc[mi][ni] = __builtin_amdgcn_mfma_f32_16x16x32_f16(af[mi], bf[ni], acc[mi][ni], 0, 0, 0);
        }
        __syncthreads();
    }
    int rq = (lane >> 4) * 4, cq = lane & 15;
#pragma unroll
    for (int mi = 0; mi < 4; mi++)
#pragma unroll
        for (int ni = 0; ni < 3; ni++) {
            int gc = wn * 48 + ni * 16 + cq;
            if (gc < 84) {
#pragma unroll
                for (int j = 0; j < 4; j++) {
                    int gr = row0 + wm * 64 + mi * 16 + rq + j;
                    C[(size_t)gr * 84 + gc] = (_Float16)acc[mi][ni][j];
                }
            }
        }
}

// ---------------- recurrence: one WG (1024 thr) per batch, 150 steps ----------------
__global__ __launch_bounds__(1024) void k_recur2(
    const _Float16* __restrict__ uah,  // [B][T][F] fp16
    const _Float16* __restrict__ xg,   // [B][T][84] fp16
    const float* __restrict__ Wa,      // [U][F]
    const float* __restrict__ Va,      // [F]
    const float* __restrict__ Ba1,     // [F]
    const float* __restrict__ grk,     // [U][3U]
    const float* __restrict__ gbias,   // [2][3U]
    float* __restrict__ out)           // [B][T][U]
{
    __shared__ _Float16 sWa[U_ * F_];      // 56 KB  [u][f] fp16
    __shared__ _Float16 sXG[T_ * TU3];     // 25.2 KB
    __shared__ float sWaS[F_];             // 4 KB
    __shared__ float sScore[160];
    __shared__ float sPart[8 * TU3];
    __shared__ float sGrk[U_ * TU3];       // 9.4 KB
    __shared__ float sHz[TU3];
    __shared__ float sH[U_];

    int b = blockIdx.x;
    int tid = threadIdx.x;
    int lane = tid & 63, wvid = tid >> 6;  // 16 waves

    // ---- one-time LDS + register hoists
    for (int i = tid; i < U_ * F_; i += 1024) sWa[i] = (_Float16)Wa[i];
    {
        const _Float16* xgb = xg + (size_t)b * T_ * TU3;
        for (int i = tid; i < T_ * TU3; i += 1024) sXG[i] = xgb[i];
    }
    for (int i = tid; i < U_ * TU3; i += 1024) sGrk[i] = grk[i];
    if (tid < U_) sH[tid] = 0.f;

    float rBa1 = Ba1[tid];
    float rV0[8], rV1[8];
    {
        f4 a0 = *(const f4*)(Va + 8 * lane);
        f4 a1 = *(const f4*)(Va + 8 * lane + 4);
        f4 b0 = *(const f4*)(Va + 512 + 8 * lane);
        f4 b1 = *(const f4*)(Va + 512 + 8 * lane + 4);
#pragma unroll
        for (int e = 0; e < 4; ++e) { rV0[e] = a0[e]; rV0[4 + e] = a1[e]; rV1[e] = b0[e]; rV1[4 + e] = b1[e]; }
    }
    int p4c = tid / TU3, p4j = tid - p4c * TU3;
    bool p4on = tid < 8 * TU3;             // 672 threads
    bool hzon = (tid >= 896) && (tid < 896 + TU3);
    int hj = tid - 896;
    float rGb1 = hzon ? gbias[TU3 + hj] : 0.f;
    float rG0 = 0.f, rG1 = 0.f, rG2 = 0.f;
    if (tid < U_) { rG0 = gbias[tid]; rG1 = gbias[U_ + tid]; rG2 = gbias[2 * U_ + tid]; }
    __syncthreads();

    const _Float16* ub = uah + (size_t)b * T_ * F_;
    float* ob = out + (size_t)b * T_ * U_;

    for (int t = 0; t < T_; ++t) {
        // ---- P1: WaS[f] = Ba1[f] + h @ Wa[:,f]  (f = tid; Wa in LDS)
        {
            float acc = rBa1;
#pragma unroll
            for (int u = 0; u < U_; ++u) acc += sH[u] * (float)sWa[u * F_ + tid];
            sWaS[tid] = acc;
        }
        __syncthreads();   // B1
        // ---- P1b: hoist this lane's 16 WaS values into registers
        float rW0[8], rW1[8];
        {
            f4 a0 = *(const f4*)(sWaS + 8 * lane);
            f4 a1 = *(const f4*)(sWaS + 8 * lane + 4);
            f4 b0 = *(const f4*)(sWaS + 512 + 8 * lane);
            f4 b1 = *(const f4*)(sWaS + 512 + 8 * lane + 4);
#pragma unroll
            for (int e = 0; e < 4; ++e) { rW0[e] = a0[e]; rW0[4 + e] = a1[e]; rW1[e] = b0[e]; rW1[4 + e] = b1[e]; }
        }
        // ---- P2: scores, one row per wave-iteration; h8 loads, manual prefetch
        {
            int r = wvid;
            const h8* pr = (const h8*)(ub + (size_t)r * F_);
            h8 u0 = pr[lane], u1 = pr[64 + lane];
            while (r < T_) {
                int rn = r + 16;
                h8 n0, n1;
                if (rn < T_) {
                    const h8* pn = (const h8*)(ub + (size_t)rn * F_);
                    n0 = pn[lane]; n1 = pn[64 + lane];
                }
                float acc = 0.f;
#pragma unroll
                for (int e = 0; e < 8; ++e) {
                    float s0 = (float)u0[e] + rW0[e];
                    acc += fast_tanh(s0) * rV0[e];
                    float s1 = (float)u1[e] + rW1[e];
                    acc += fast_tanh(s1) * rV1[e];
                }
#pragma unroll
                for (int off = 32; off; off >>= 1) acc += __shfl_xor(acc, off, 64);
                if (lane == 0) sScore[r] = acc;
                u0 = n0; u1 = n1; r = rn;
            }
        }
        __syncthreads();   // B2
        // ---- P3: softmax over 150 scores (wave 0)
        if (wvid == 0) {
            float v0 = (lane < T_)       ? sScore[lane]       : -1e30f;
            float v1 = (lane + 64 < T_)  ? sScore[lane + 64]  : -1e30f;
            float v2 = (lane + 128 < T_) ? sScore[lane + 128] : -1e30f;
            float m = fmaxf(v0, fmaxf(v1, v2));
#pragma unroll
            for (int off = 32; off; off >>= 1) m = fmaxf(m, __shfl_xor(m, off, 64));
            float e0 = (lane < T_)       ? fast_exp(v0 - m) : 0.f;
            float e1 = (lane + 64 < T_)  ? fast_exp(v1 - m) : 0.f;
            float e2 = (lane + 128 < T_) ? fast_exp(v2 - m) : 0.f;
            float s = e0 + e1 + e2;
#pragma unroll
            for (int off = 32; off; off >>= 1) s += __shfl_xor(s, off, 64);
            float rs = __builtin_amdgcn_rcpf(s);
            if (lane < T_)       sScore[lane]       = e0 * rs;
            if (lane + 64 < T_)  sScore[lane + 64]  = e1 * rs;
            if (lane + 128 < T_) sScore[lane + 128] = e2 * rs;
        }
        __syncthreads();   // B3
        // ---- P4: xz partials (a . XG) + hz = h @ grk
        if (p4on) {
            float acc = 0.f;
            for (int r = p4c; r < T_; r += 8) acc += sScore[r] * (float)sXG[r * TU3 + p4j];
            sPart[p4c * TU3 + p4j] = acc;
        }
        if (hzon) {
            float hz = rGb1;
#pragma unroll
            for (int u = 0; u < U_; ++u) hz += sH[u] * sGrk[u * TU3 + hj];
            sHz[hj] = hz;
        }
        __syncthreads();   // B4
        // ---- P5: gates + state update + output (threads 0..27)
        if (tid < U_) {
            float x0 = rG0, x1 = rG1, x2 = rG2;
#pragma unroll
            for (int c = 0; c < 8; ++c) {
                x0 += sPart[c * TU3 + tid];
                x1 += sPart[c * TU3 + U_ + tid];
                x2 += sPart[c * TU3 + 2 * U_ + tid];
            }
            float z  = fast_sigmoid(x0 + sHz[tid]);
            float r  = fast_sigmoid(x1 + sHz[U_ + tid]);
            float hh = fast_tanh(x2 + r * sHz[2 * U_ + tid]);
            float hn = z * sH[tid] + (1.f - z) * hh;
            sH[tid] = hn;
            ob[(size_t)t * U_ + tid] = hn;
        }
        __syncthreads();   // B5
    }
}

extern "C" void kernel_launch(void* const* d_in, const int* in_sizes, int n_in,
                              void* d_out, int out_size, void* d_ws, size_t ws_size,
                              hipStream_t stream) {
    (void)in_sizes; (void)n_in; (void)out_size; (void)ws_size;
    const float* x   = (const float*)d_in[0];
    const float* Wa  = (const float*)d_in[1];
    const float* Ua  = (const float*)d_in[2];
    const float* Va  = (const float*)d_in[3];
    const float* Ba1 = (const float*)d_in[4];
    const float* Ba2 = (const float*)d_in[5];
    // d_in[6] = Ba3: softmax shift-invariant, dropped.
    const float* gk  = (const float*)d_in[7];
    const float* grk = (const float*)d_in[8];
    const float* gb  = (const float*)d_in[9];
    float* out = (float*)d_out;

    const size_t NX = (size_t)B_ * T_ * F_;          // 39,321,600
    _Float16* xh  = (_Float16*)d_ws;                 // NX halves
    _Float16* uat = xh + NX;                         // 1 Mi halves
    _Float16* uah = uat + (size_t)F_ * F_;           // NX halves
    _Float16* xgh = uah + NX;                        // 38400*84 halves (~158 MB total)

    k_cvt<<<2048, 256, 0, stream>>>(x, xh, (int)(NX / 4));
    k_cvt_transpose<<<(F_ * F_) / 256, 256, 0, stream>>>(Ua, uat);
    dim3 gg(F_ / BN, (B_ * T_) / BM);                // (8, 300)
    k_gemm<<<gg, 256, 0, stream>>>(xh, uat, Ba2, uah);
    k_gemm_xg<<<(B_ * T_) / 128, 256, 0, stream>>>(xh, gk, xgh);
    k_recur2<<<B_, 1024, 0, stream>>>(uah, xgh, Wa, Va, Ba1, grk, gb, out);
}

// Round 4
// 2230.706 us; speedup vs baseline: 3.0686x; 1.1958x over previous
//
#include <hip/hip_runtime.h>
#include <hip/hip_bf16.h>

// CascadedAttention on MI355X — round 3.
// vs round 2: (a) P2 inner tanh folded to {fma_mix, exp2, add, rcp, fma} via
// fmaf((float)h16, C2, w2) and hoisted SumVa / -2Va; (b) softmax max-shift
// removed (|score| <= sum|Va| ~ 41 << 88), exp fused into score store, P3 phase
// and its barrier deleted; denominator reduced by wave 13 in P4, normalization
// by rcp(den) in P5. 4 barriers/step.

typedef _Float16 h8 __attribute__((ext_vector_type(8)));
typedef _Float16 h4 __attribute__((ext_vector_type(4)));
typedef _Float16 h2 __attribute__((ext_vector_type(2)));
typedef float    f4 __attribute__((ext_vector_type(4)));
typedef float    f2 __attribute__((ext_vector_type(2)));

#define B_   256
#define T_   150
#define F_   1024
#define U_   28
#define TU3  84   // 3*U

#define C2LOG2E 2.8853900817779268f   // 2*log2(e)
#define LOG2E   1.4426950408889634f

__device__ __forceinline__ float fast_exp(float x) {
    return __builtin_amdgcn_exp2f(x * LOG2E);
}
__device__ __forceinline__ float fast_sigmoid(float x) {
    float e = __builtin_amdgcn_exp2f(-x * LOG2E);
    return __builtin_amdgcn_rcpf(1.0f + e);
}
__device__ __forceinline__ float fast_tanh(float x) {
    float e = __builtin_amdgcn_exp2f(x * C2LOG2E);
    float r = __builtin_amdgcn_rcpf(e + 1.0f);
    return 1.0f - 2.0f * r;
}

// ---------------- fp32 -> fp16 convert ----------------
__global__ void k_cvt(const float* __restrict__ in, _Float16* __restrict__ out, int n4) {
    int i = blockIdx.x * blockDim.x + threadIdx.x;
    int stride = gridDim.x * blockDim.x;
    const f4* in4 = (const f4*)in;
    h4* out4 = (h4*)out;
    for (; i < n4; i += stride) {
        f4 v = in4[i];
        h4 o;
        o[0] = (_Float16)v[0]; o[1] = (_Float16)v[1];
        o[2] = (_Float16)v[2]; o[3] = (_Float16)v[3];
        out4[i] = o;
    }
}

// ---------------- Ua (1024x1024) -> fp16 transposed ----------------
__global__ void k_cvt_transpose(const float* __restrict__ in, _Float16* __restrict__ out) {
    int idx = blockIdx.x * blockDim.x + threadIdx.x;
    int r = idx >> 10, c = idx & 1023;
    out[(c << 10) + r] = (_Float16)in[idx];
}

// ---------------- GEMM: UaH = x_h @ Ua + Ba2 (M=38400,N=1024,K=1024) ----------------
#define BM 128
#define BN 128
#define BK 32
#define LDT 40

__global__ __launch_bounds__(256) void k_gemm(
    const _Float16* __restrict__ A,
    const _Float16* __restrict__ Bt,
    const float*    __restrict__ bias,
    _Float16*       __restrict__ C)
{
    __shared__ _Float16 As[BM][LDT];
    __shared__ _Float16 Bs[BN][LDT];
    const int K = 1024;
    int bm = blockIdx.y, bn = blockIdx.x;
    int tid = threadIdx.x;
    int lane = tid & 63, wid = tid >> 6;
    int wm = wid >> 1, wn = wid & 1;
    f4 acc[4][4];
#pragma unroll
    for (int i = 0; i < 4; i++)
#pragma unroll
        for (int j = 0; j < 4; j++) { f4 z = {0.f, 0.f, 0.f, 0.f}; acc[i][j] = z; }

    int row0 = bm * BM, col0 = bn * BN;
    for (int kt = 0; kt < K; kt += BK) {
#pragma unroll
        for (int p = 0; p < 2; ++p) {
            int s = tid + p * 256;
            int r = s >> 2, seg = s & 3;
            h8 va = *(const h8*)(A  + (size_t)(row0 + r) * K + kt + seg * 8);
            *(h8*)(&As[r][seg * 8]) = va;
            h8 vb = *(const h8*)(Bt + (size_t)(col0 + r) * K + kt + seg * 8);
            *(h8*)(&Bs[r][seg * 8]) = vb;
        }
        __syncthreads();
        int kq = (lane >> 4) * 8;
        h8 af[4], bf[4];
#pragma unroll
        for (int mi = 0; mi < 4; mi++) af[mi] = *(const h8*)(&As[wm * 64 + mi * 16 + (lane & 15)][kq]);
#pragma unroll
        for (int ni = 0; ni < 4; ni++) bf[ni] = *(const h8*)(&Bs[wn * 64 + ni * 16 + (lane & 15)][kq]);
#pragma unroll
        for (int mi = 0; mi < 4; mi++)
#pragma unroll
            for (int ni = 0; ni < 4; ni++)
                acc[mi][ni] = __builtin_amdgcn_mfma_f32_16x16x32_f16(af[mi], bf[ni], acc[mi][ni], 0, 0, 0);
        __syncthreads();
    }
    int rq = (lane >> 4) * 4, cq = lane & 15;
#pragma unroll
    for (int mi = 0; mi < 4; mi++)
#pragma unroll
        for (int ni = 0; ni < 4; ni++) {
            int gc = col0 + wn * 64 + ni * 16 + cq;
            float bv = bias[gc];
#pragma unroll
            for (int j = 0; j < 4; j++) {
                int gr = row0 + wm * 64 + mi * 16 + rq + j;
                C[(size_t)gr * 1024 + gc] = (_Float16)(acc[mi][ni][j] + bv);
            }
        }
}

// ---------------- GEMM: XG = x_h @ gk (M=38400, N=84 pad 96, K=1024), fp16 out ---------
#define XLD 72

__global__ __launch_bounds__(256) void k_gemm_xg(
    const _Float16* __restrict__ A,
    const float*    __restrict__ gk,
    _Float16*       __restrict__ C)
{
    __shared__ _Float16 As[128][XLD];
    __shared__ _Float16 Bs[96][XLD];
    int tid = threadIdx.x;
    int lane = tid & 63, wid = tid >> 6;
    int wm = wid >> 1, wn = wid & 1;
    int row0 = blockIdx.x * 128;
    f4 acc[4][3];
#pragma unroll
    for (int i = 0; i < 4; i++)
#pragma unroll
        for (int j = 0; j < 3; j++) { f4 z = {0.f, 0.f, 0.f, 0.f}; acc[i][j] = z; }

    if (tid < 432) { h2 z; z[0] = (_Float16)0.f; z[1] = (_Float16)0.f; ((h2*)&Bs[84][0])[tid] = z; }

    for (int kt = 0; kt < 1024; kt += 64) {
#pragma unroll
        for (int p = 0; p < 4; ++p) {
            int s = tid + p * 256;
            int r = s >> 3, seg = s & 7;
            *(h8*)(&As[r][seg * 8]) = *(const h8*)(A + (size_t)(row0 + r) * 1024 + kt + seg * 8);
        }
#pragma unroll
        for (int p = 0; p < 21; ++p) {
            int s = tid + p * 256;
            int j = s % 84, k = s / 84;
            Bs[j][k] = (_Float16)gk[(size_t)(kt + k) * 84 + j];
        }
        __syncthreads();
#pragma unroll
        for (int kk = 0; kk < 64; kk += 32) {
            int kq = kk + (lane >> 4) * 8;
            h8 af[4], bf[3];
#pragma unroll
            for (int mi = 0; mi < 4; mi++) af[mi] = *(const h8*)(&As[wm * 64 + mi * 16 + (lane & 15)][kq]);
#pragma unroll
            for (int ni = 0; ni < 3; ni++) bf[ni] = *(const h8*)(&Bs[wn * 48 + ni * 16 + (lane & 15)][kq]);
#pragma unroll
            for (int mi = 0; mi < 4; mi++)
#pragma unroll
                for (int ni = 0; ni < 3; ni++)
                    acc[mi][ni] = __builtin_amdgcn_mfma_f32_16x16x32_f16(af[mi], bf[ni], acc[mi][ni], 0, 0, 0);
        }
        __syncthreads();
    }
    int rq = (lane >> 4) * 4, cq = lane & 15;
#pragma unroll
    for (int mi = 0; mi < 4; mi++)
#pragma unroll
        for (int ni = 0; ni < 3; ni++) {
            int gc = wn * 48 + ni * 16 + cq;
            if (gc < 84) {
#pragma unroll
                for (int j = 0; j < 4; j++) {
                    int gr = row0 + wm * 64 + mi * 16 + rq + j;
                    C[(size_t)gr * 84 + gc] = (_Float16)acc[mi][ni][j];
                }
            }
        }
}

// ---------------- recurrence: one WG (1024 thr) per batch, 150 steps ----------------
__global__ __launch_bounds__(1024) void k_recur2(
    const _Float16* __restrict__ uah,  // [B][T][F] fp16
    const _Float16* __restrict__ xg,   // [B][T][84] fp16
    const float* __restrict__ Wa,      // [U][F]
    const float* __restrict__ Va,      // [F]
    const float* __restrict__ Ba1,     // [F]
    const float* __restrict__ grk,     // [U][3U]
    const float* __restrict__ gbias,   // [2][3U]
    float* __restrict__ out)           // [B][T][U]
{
    __shared__ _Float16 sWa[U_ * F_];      // 56 KB
    __shared__ _Float16 sXG[T_ * TU3];     // 25.2 KB
    __shared__ float sWaS[F_];             // 4 KB
    __shared__ float sScore[160];          // holds p_r = exp(score_r), unnormalized
    __shared__ float sPart[8 * TU3];
    __shared__ float sGrk[U_ * TU3];       // 9.4 KB
    __shared__ float sHz[TU3];
    __shared__ float sH[U_];
    __shared__ float sDen;

    int b = blockIdx.x;
    int tid = threadIdx.x;
    int lane = tid & 63, wvid = tid >> 6;  // 16 waves

    // ---- one-time LDS + register hoists
    for (int i = tid; i < U_ * F_; i += 1024) sWa[i] = (_Float16)Wa[i];
    {
        const _Float16* xgb = xg + (size_t)b * T_ * TU3;
        for (int i = tid; i < T_ * TU3; i += 1024) sXG[i] = xgb[i];
    }
    for (int i = tid; i < U_ * TU3; i += 1024) sGrk[i] = grk[i];
    if (tid < U_) sH[tid] = 0.f;

    float rBa1 = Ba1[tid];
    // rA = -2*Va (tanh = 1 - 2r), vaBase = sum of this lane's 16 Va values
    float rA0[8], rA1[8], vaBase = 0.f;
    {
        f4 a0 = *(const f4*)(Va + 8 * lane);
        f4 a1 = *(const f4*)(Va + 8 * lane + 4);
        f4 b0 = *(const f4*)(Va + 512 + 8 * lane);
        f4 b1 = *(const f4*)(Va + 512 + 8 * lane + 4);
#pragma unroll
        for (int e = 0; e < 4; ++e) {
            rA0[e] = -2.f * a0[e]; rA0[4 + e] = -2.f * a1[e];
            rA1[e] = -2.f * b0[e]; rA1[4 + e] = -2.f * b1[e];
            vaBase += a0[e] + a1[e] + b0[e] + b1[e];
        }
    }
    int p4c = tid / TU3, p4j = tid - p4c * TU3;
    bool p4on = tid < 8 * TU3;             // threads 0..671
    bool denon = (wvid == 13);             // threads 832..895
    bool hzon = (tid >= 896) && (tid < 896 + TU3);  // 896..979
    int hj = tid - 896;
    float rGb1 = hzon ? gbias[TU3 + hj] : 0.f;
    float rG0 = 0.f, rG1 = 0.f, rG2 = 0.f;
    if (tid < U_) { rG0 = gbias[tid]; rG1 = gbias[U_ + tid]; rG2 = gbias[2 * U_ + tid]; }
    __syncthreads();

    const _Float16* ub = uah + (size_t)b * T_ * F_;
    float* ob = out + (size_t)b * T_ * U_;

    for (int t = 0; t < T_; ++t) {
        // ---- P1: WaS[f] = Ba1[f] + h @ Wa[:,f]
        {
            float acc = rBa1;
#pragma unroll
            for (int u = 0; u < U_; ++u) acc += sH[u] * (float)sWa[u * F_ + tid];
            sWaS[tid] = acc;
        }
        __syncthreads();   // B1
        // ---- P1b: per-lane WaS slice, pre-scaled by 2*log2e (exp2 arg units)
        float rW0[8], rW1[8];
        {
            f4 a0 = *(const f4*)(sWaS + 8 * lane);
            f4 a1 = *(const f4*)(sWaS + 8 * lane + 4);
            f4 b0 = *(const f4*)(sWaS + 512 + 8 * lane);
            f4 b1 = *(const f4*)(sWaS + 512 + 8 * lane + 4);
#pragma unroll
            for (int e = 0; e < 4; ++e) {
                rW0[e] = a0[e] * C2LOG2E; rW0[4 + e] = a1[e] * C2LOG2E;
                rW1[e] = b0[e] * C2LOG2E; rW1[4 + e] = b1[e] * C2LOG2E;
            }
        }
        // ---- P2: p_r = exp(score_r); inner: fma_mix, exp2, add, rcp, fma
        {
            int r = wvid;
            const h8* pr = (const h8*)(ub + (size_t)r * F_);
            h8 u0 = pr[lane], u1 = pr[64 + lane];
            while (r < T_) {
                int rn = r + 16;
                h8 n0, n1;
                if (rn < T_) {
                    const h8* pn = (const h8*)(ub + (size_t)rn * F_);
                    n0 = pn[lane]; n1 = pn[64 + lane];
                }
                float acc = vaBase;
#pragma unroll
                for (int e = 0; e < 8; ++e) {
                    float t0 = fmaf((float)u0[e], C2LOG2E, rW0[e]);  // v_fma_mix
                    float r0 = __builtin_amdgcn_rcpf(__builtin_amdgcn_exp2f(t0) + 1.0f);
                    acc = fmaf(rA0[e], r0, acc);
                    float t1 = fmaf((float)u1[e], C2LOG2E, rW1[e]);
                    float r1 = __builtin_amdgcn_rcpf(__builtin_amdgcn_exp2f(t1) + 1.0f);
                    acc = fmaf(rA1[e], r1, acc);
                }
#pragma unroll
                for (int off = 32; off; off >>= 1) acc += __shfl_xor(acc, off, 64);
                if (lane == 0) sScore[r] = fast_exp(acc);   // no max-shift: |score| <~ 45 < 88
                u0 = n0; u1 = n1; r = rn;
            }
        }
        __syncthreads();   // B2
        // ---- P4: xz partials (p . XG) + denominator + hz = h @ grk
        if (p4on) {
            float acc = 0.f;
            for (int r = p4c; r < T_; r += 8)
                acc = fmaf((float)sXG[r * TU3 + p4j], sScore[r], acc);  // fma_mix
            sPart[p4c * TU3 + p4j] = acc;
        }
        if (denon) {
            float d0 = (lane < T_)       ? sScore[lane]       : 0.f;
            float d1 = (lane + 64 < T_)  ? sScore[lane + 64]  : 0.f;
            float d2 = (lane + 128 < T_) ? sScore[lane + 128] : 0.f;
            float ds = d0 + d1 + d2;
#pragma unroll
            for (int off = 32; off; off >>= 1) ds += __shfl_xor(ds, off, 64);
            if (lane == 0) sDen = ds;
        }
        if (hzon) {
            float hz = rGb1;
#pragma unroll
            for (int u = 0; u < U_; ++u) hz += sH[u] * sGrk[u * TU3 + hj];
            sHz[hj] = hz;
        }
        __syncthreads();   // B4
        // ---- P5: gates + state update + output (threads 0..27)
        if (tid < U_) {
            float rs = __builtin_amdgcn_rcpf(sDen);
            float x0 = 0.f, x1 = 0.f, x2 = 0.f;
#pragma unroll
            for (int c = 0; c < 8; ++c) {
                x0 += sPart[c * TU3 + tid];
                x1 += sPart[c * TU3 + U_ + tid];
                x2 += sPart[c * TU3 + 2 * U_ + tid];
            }
            x0 = fmaf(x0, rs, rG0);
            x1 = fmaf(x1, rs, rG1);
            x2 = fmaf(x2, rs, rG2);
            float z  = fast_sigmoid(x0 + sHz[tid]);
            float r  = fast_sigmoid(x1 + sHz[U_ + tid]);
            float hh = fast_tanh(x2 + r * sHz[2 * U_ + tid]);
            float hn = z * sH[tid] + (1.f - z) * hh;
            sH[tid] = hn;
            ob[(size_t)t * U_ + tid] = hn;
        }
        __syncthreads();   // B5
    }
}

extern "C" void kernel_launch(void* const* d_in, const int* in_sizes, int n_in,
                              void* d_out, int out_size, void* d_ws, size_t ws_size,
                              hipStream_t stream) {
    (void)in_sizes; (void)n_in; (void)out_size; (void)ws_size;
    const float* x   = (const float*)d_in[0];
    const float* Wa  = (const float*)d_in[1];
    const float* Ua  = (const float*)d_in[2];
    const float* Va  = (const float*)d_in[3];
    const float* Ba1 = (const float*)d_in[4];
    const float* Ba2 = (const float*)d_in[5];
    // d_in[6] = Ba3: softmax shift-invariant, dropped.
    const float* gk  = (const float*)d_in[7];
    const float* grk = (const float*)d_in[8];
    const float* gb  = (const float*)d_in[9];
    float* out = (float*)d_out;

    const size_t NX = (size_t)B_ * T_ * F_;
    _Float16* xh  = (_Float16*)d_ws;
    _Float16* uat = xh + NX;
    _Float16* uah = uat + (size_t)F_ * F_;
    _Float16* xgh = uah + NX;

    k_cvt<<<2048, 256, 0, stream>>>(x, xh, (int)(NX / 4));
    k_cvt_transpose<<<(F_ * F_) / 256, 256, 0, stream>>>(Ua, uat);
    dim3 gg(F_ / BN, (B_ * T_) / BM);
    k_gemm<<<gg, 256, 0, stream>>>(xh, uat, Ba2, uah);
    k_gemm_xg<<<(B_ * T_) / 128, 256, 0, stream>>>(xh, gk, xgh);
    k_recur2<<<B_, 1024, 0, stream>>>(uah, xgh, Wa, Va, Ba1, grk, gb, out);
}